// Round 6
// baseline (42.352 us; speedup 1.0000x reference)
//
#include <hip/hip_runtime.h>
#include <math.h>

#define NBINS   1024
#define NPART   512     // hist grid: 512 blocks x 256 rows
#define RPB     256     // rows per block (one per thread, 64 per wave)

// ws layout: gC[NPART*NBINS] block partials (2MB). No global-memory races except
// 32 f32 atomicAdds on out[0] in reduce (threshold 0.2 >> ulp noise).

__global__ __launch_bounds__(256, 2) void hist_kernel(const float* __restrict__ act,
                                                      float* __restrict__ gC,
                                                      float* __restrict__ out,
                                                      int rows)
{
    // Per-wave private 64-row operand buffers, XOR-swizzled at float4 granularity:
    // writes (lanes = different rows) conflict-free; reads (uniform row t) are
    // 8-address broadcasts -> conflict-free with NO padding.
    __shared__ __align__(16) float Phi_s[4][64][32];   // 32KB
    __shared__ __align__(16) float Plo_s[4][64][32];   // 32KB
    __shared__ float C_lds[NBINS];                     // 4KB

    const int tid  = threadIdx.x;
    const int wav  = tid >> 6;
    const int lane = tid & 63;

    #pragma unroll
    for (int k = 0; k < NBINS / 256; ++k)
        C_lds[tid + k * 256] = 0.0f;

    if (blockIdx.x == 0 && tid == 0) out[0] = 0.0f;   // reduce accumulates later

    const int row = blockIdx.x * RPB + tid;

    float v[10];
    float valid = 1.0f;
    if (row < rows) {
        const float2* a2 = (const float2*)(act + (size_t)row * 10);
        #pragma unroll
        for (int k = 0; k < 5; ++k) {
            float2 t = a2[k];
            v[2 * k] = t.x; v[2 * k + 1] = t.y;
        }
    } else {
        valid = 0.0f;
        #pragma unroll
        for (int k = 0; k < 10; ++k) v[k] = 0.0f;
    }

    // Product trees. r=0 is the MSB of the 10-bit joint index.
    float hi[32], lo[32];
    {
        float t2[2], t4[4], t8[8], t16[16];
        t2[0] = valid * (1.0f - v[0]); t2[1] = valid * v[0];
        #pragma unroll
        for (int k = 0; k < 4; ++k)  t4[k]  = t2[k >> 1]  * ((k & 1) ? v[1] : 1.0f - v[1]);
        #pragma unroll
        for (int k = 0; k < 8; ++k)  t8[k]  = t4[k >> 1]  * ((k & 1) ? v[2] : 1.0f - v[2]);
        #pragma unroll
        for (int k = 0; k < 16; ++k) t16[k] = t8[k >> 1]  * ((k & 1) ? v[3] : 1.0f - v[3]);
        #pragma unroll
        for (int k = 0; k < 32; ++k) hi[k]  = t16[k >> 1] * ((k & 1) ? v[4] : 1.0f - v[4]);
    }
    {
        float t2[2], t4[4], t8[8], t16[16];
        t2[0] = 1.0f - v[5]; t2[1] = v[5];
        #pragma unroll
        for (int k = 0; k < 4; ++k)  t4[k]  = t2[k >> 1]  * ((k & 1) ? v[6] : 1.0f - v[6]);
        #pragma unroll
        for (int k = 0; k < 8; ++k)  t8[k]  = t4[k >> 1]  * ((k & 1) ? v[7] : 1.0f - v[7]);
        #pragma unroll
        for (int k = 0; k < 16; ++k) t16[k] = t8[k >> 1]  * ((k & 1) ? v[8] : 1.0f - v[8]);
        #pragma unroll
        for (int k = 0; k < 32; ++k) lo[k]  = t16[k >> 1] * ((k & 1) ? v[9] : 1.0f - v[9]);
    }

    // Swizzled b128 stores of this thread's row (slot = lane) into its wave's buffer.
    {
        float4* ph4 = (float4*)&Phi_s[wav][lane][0];
        float4* pl4 = (float4*)&Plo_s[wav][lane][0];
        const int sw = lane & 7;
        #pragma unroll
        for (int j = 0; j < 8; ++j)
            ph4[j ^ sw] = make_float4(hi[4*j], hi[4*j+1], hi[4*j+2], hi[4*j+3]);
        #pragma unroll
        for (int j = 0; j < 8; ++j)
            pl4[j ^ sw] = make_float4(lo[4*j], lo[4*j+1], lo[4*j+2], lo[4*j+3]);
    }

    __syncthreads();

    // Phase 2: each wave accumulates 32x32 over ITS OWN 64 rows.
    // Lane owns 4x4 tile (i0 = (lane>>3)*4, j0 = (lane&7)*4).
    const int gph = lane >> 3;    // float4 group of ph
    const int gpl = lane & 7;     // float4 group of pl

    float c[4][4];
    #pragma unroll
    for (int ii = 0; ii < 4; ++ii)
        #pragma unroll
        for (int jj = 0; jj < 4; ++jj) c[ii][jj] = 0.0f;

    #pragma unroll 8
    for (int t = 0; t < 64; ++t) {
        const int s = t & 7;
        const float4 ph = *(const float4*)&Phi_s[wav][t][(gph ^ s) << 2];
        const float4 pl = *(const float4*)&Plo_s[wav][t][(gpl ^ s) << 2];
        const float phv[4] = {ph.x, ph.y, ph.z, ph.w};
        const float plv[4] = {pl.x, pl.y, pl.z, pl.w};
        #pragma unroll
        for (int ii = 0; ii < 4; ++ii)
            #pragma unroll
            for (int jj = 0; jj < 4; ++jj)
                c[ii][jj] = fmaf(phv[ii], plv[jj], c[ii][jj]);
    }

    // combine 4 waves via LDS atomics (each wave's 64 lanes cover all 1024 bins)
    const int i0 = gph * 4;
    const int j0 = gpl * 4;
    #pragma unroll
    for (int ii = 0; ii < 4; ++ii)
        #pragma unroll
        for (int jj = 0; jj < 4; ++jj)
            atomicAdd(&C_lds[(i0 + ii) * 32 + (j0 + jj)], c[ii][jj]);

    __syncthreads();

    // coalesced plain-store of the block's 4KB partial
    float4* dst4 = (float4*)(gC + (size_t)blockIdx.x * NBINS);
    dst4[tid] = ((const float4*)C_lds)[tid];
}

// Fused reduce + entropy. 32 blocks x 256 threads; block owns 32 bins.
__global__ __launch_bounds__(256) void reduce_kernel(const float* __restrict__ gC,
                                                     float* __restrict__ out,
                                                     float invB)
{
    __shared__ float red[8][32];
    const int tid = threadIdx.x;
    const int g   = tid >> 5;            // 0..7
    const int i   = tid & 31;
    const int bin = blockIdx.x * 32 + i;

    float s = 0.0f;
    for (int k = g; k < NPART; k += 8)           // 64 coalesced strided reads
        s += gC[(size_t)k * NBINS + bin];
    red[g][i] = s;
    __syncthreads();

    if (tid < 64) {
        float e = 0.0f;
        if (tid < 32) {
            float t = 0.0f;
            #pragma unroll
            for (int k = 0; k < 8; ++k) t += red[k][tid];
            const float p = t * invB;
            e = p * log2f(fmaxf(p, 1e-12f));     // sum p*log2(clip(p)) = -joint_h
        }
        // xor-reduce: offsets stay within the 32-lane halves, lanes 32-63 harmless
        #pragma unroll
        for (int off = 16; off > 0; off >>= 1) e += __shfl_xor(e, off);
        if (tid == 0) atomicAdd(out, e);
    }
}

extern "C" void kernel_launch(void* const* d_in, const int* in_sizes, int n_in,
                              void* d_out, int out_size, void* d_ws, size_t ws_size,
                              hipStream_t stream)
{
    const float* act = (const float*)d_in[0];
    const int rows = in_sizes[0] / 10;        // B = 131072 = 512 * 256
    float* gC = (float*)d_ws;                 // NPART x NBINS partials (2MB)
    float* out = (float*)d_out;

    hist_kernel<<<NPART, 256, 0, stream>>>(act, gC, out, rows);
    reduce_kernel<<<32, 256, 0, stream>>>(gC, out, 1.0f / (float)rows);
}

// Round 7
// 39.421 us; speedup vs baseline: 1.0743x; 1.0743x over previous
//
#include <hip/hip_runtime.h>
#include <hip/hip_bf16.h>
#include <math.h>

#define NBINS   1024
#define NPART   512     // hist grid: 512 blocks x 256 rows (4 waves x 64 rows)
#define LSTRIDE 72      // ushorts per bin-row: 144B (16B-aligned), writes 2/bank = free

typedef __attribute__((ext_vector_type(8)))  short short8;   // 8 bf16 = 4 VGPR
typedef __attribute__((ext_vector_type(16))) float f32x16;   // MFMA 32x32 acc

__global__ __launch_bounds__(256, 2) void hist_kernel(const float* __restrict__ act,
                                                      float* __restrict__ gC,
                                                      float* __restrict__ out,
                                                      int rows)
{
    // Per-wave bf16 operand panels, [bin][row-slot]: phase-2 lane reads its bin's
    // 8 consecutive row-slots as one 16B ds_read_b128.
    __shared__ ushort Phi_u[4][32][LSTRIDE];   // 18KB
    __shared__ ushort Plo_u[4][32][LSTRIDE];   // 18KB
    __shared__ float  C_lds[NBINS];            // 4KB   (41KB total -> 2+ blocks/CU)

    const int tid  = threadIdx.x;
    const int wav  = tid >> 6;
    const int lane = tid & 63;

    #pragma unroll
    for (int k = 0; k < NBINS / 256; ++k)
        C_lds[tid + k * 256] = 0.0f;

    if (blockIdx.x == 0 && tid == 0) out[0] = 0.0f;   // reduce atomically adds later

    const int row = blockIdx.x * 256 + tid;

    float v[10];
    float valid = 1.0f;
    if (row < rows) {
        const float2* a2 = (const float2*)(act + (size_t)row * 10);
        #pragma unroll
        for (int k = 0; k < 5; ++k) {
            float2 t = a2[k];
            v[2 * k] = t.x; v[2 * k + 1] = t.y;
        }
    } else {
        valid = 0.0f;
        #pragma unroll
        for (int k = 0; k < 10; ++k) v[k] = 0.0f;
    }

    // Product trees (f32). r=0 is the MSB of the 10-bit joint index.
    float hi[32], lo[32];
    {
        float t2[2], t4[4], t8[8], t16[16];
        t2[0] = valid * (1.0f - v[0]); t2[1] = valid * v[0];
        #pragma unroll
        for (int k = 0; k < 4; ++k)  t4[k]  = t2[k >> 1]  * ((k & 1) ? v[1] : 1.0f - v[1]);
        #pragma unroll
        for (int k = 0; k < 8; ++k)  t8[k]  = t4[k >> 1]  * ((k & 1) ? v[2] : 1.0f - v[2]);
        #pragma unroll
        for (int k = 0; k < 16; ++k) t16[k] = t8[k >> 1]  * ((k & 1) ? v[3] : 1.0f - v[3]);
        #pragma unroll
        for (int k = 0; k < 32; ++k) hi[k]  = t16[k >> 1] * ((k & 1) ? v[4] : 1.0f - v[4]);
    }
    {
        float t2[2], t4[4], t8[8], t16[16];
        t2[0] = 1.0f - v[5]; t2[1] = v[5];
        #pragma unroll
        for (int k = 0; k < 4; ++k)  t4[k]  = t2[k >> 1]  * ((k & 1) ? v[6] : 1.0f - v[6]);
        #pragma unroll
        for (int k = 0; k < 8; ++k)  t8[k]  = t4[k >> 1]  * ((k & 1) ? v[7] : 1.0f - v[7]);
        #pragma unroll
        for (int k = 0; k < 16; ++k) t16[k] = t8[k >> 1]  * ((k & 1) ? v[8] : 1.0f - v[8]);
        #pragma unroll
        for (int k = 0; k < 32; ++k) lo[k]  = t16[k >> 1] * ((k & 1) ? v[9] : 1.0f - v[9]);
    }

    // Stage as bf16 (round-to-nearest via __float2bfloat16; compiler pairs cvt_pk).
    // Write pattern per instruction: banks (36m + lane/2) % 32 -> 2 lanes/bank = free.
    #pragma unroll
    for (int m = 0; m < 32; ++m) {
        __hip_bfloat16 bh = __float2bfloat16(hi[m]);
        __hip_bfloat16 bl = __float2bfloat16(lo[m]);
        Phi_u[wav][m][lane] = *(const ushort*)&bh;
        Plo_u[wav][m][lane] = *(const ushort*)&bl;
    }

    __syncthreads();   // covers C_lds zero-init; wave-local LDS handled by lgkmcnt

    // Phase 2: C(32x32) += Phi^T * Plo over this wave's 64 rows via 4 MFMAs.
    // Assumed CDNA fragment layout: A: (m = lane%32, k = (lane>>5)*8 + i),
    // B mirrored: (n = lane%32, same k). k-permutations are harmless as long as
    // A and B agree; (m,n)->bin mapping is irrelevant (entropy is bin-symmetric),
    // only cross-wave/block CONSISTENCY matters (same formula everywhere).
    const int m  = lane & 31;
    const int kh = (lane >> 5) * 8;      // 0 or 8

    f32x16 acc = {};
    #pragma unroll
    for (int t = 0; t < 4; ++t) {
        const short8 a = *(const short8*)&Phi_u[wav][m][kh + 16 * t];  // 16B aligned
        const short8 b = *(const short8*)&Plo_u[wav][m][kh + 16 * t];
        acc = __builtin_amdgcn_mfma_f32_32x32x16_bf16(a, b, acc, 0, 0, 0);
    }

    // Merge 4 waves: fixed bijection idx = r*64 + lane; banks = lane%32 -> 2/bank free.
    #pragma unroll
    for (int r = 0; r < 16; ++r)
        atomicAdd(&C_lds[r * 64 + lane], acc[r]);

    __syncthreads();

    // coalesced plain-store of the block's 4KB partial (no global atomics)
    float4* dst4 = (float4*)(gC + (size_t)blockIdx.x * NBINS);
    dst4[tid] = ((const float4*)C_lds)[tid];
}

// Fused reduce + entropy. 32 blocks x 256 threads; block owns 32 bins.
__global__ __launch_bounds__(256) void reduce_kernel(const float* __restrict__ gC,
                                                     float* __restrict__ out,
                                                     float invB)
{
    __shared__ float red[8][32];
    const int tid = threadIdx.x;
    const int g   = tid >> 5;            // 0..7
    const int i   = tid & 31;
    const int bin = blockIdx.x * 32 + i;

    float s = 0.0f;
    for (int k = g; k < NPART; k += 8)           // coalesced 128B segments
        s += gC[(size_t)k * NBINS + bin];
    red[g][i] = s;
    __syncthreads();

    if (tid < 64) {
        float e = 0.0f;
        if (tid < 32) {
            float t = 0.0f;
            #pragma unroll
            for (int k = 0; k < 8; ++k) t += red[k][tid];
            const float p = t * invB;
            e = p * log2f(fmaxf(p, 1e-12f));     // sum p*log2(clip(p)) = -joint_h
        }
        #pragma unroll
        for (int off = 16; off > 0; off >>= 1) e += __shfl_xor(e, off);
        if (tid == 0) atomicAdd(out, e);
    }
}

extern "C" void kernel_launch(void* const* d_in, const int* in_sizes, int n_in,
                              void* d_out, int out_size, void* d_ws, size_t ws_size,
                              hipStream_t stream)
{
    const float* act = (const float*)d_in[0];
    const int rows = in_sizes[0] / 10;        // B = 131072 = 512 * 256
    float* gC = (float*)d_ws;                 // NPART x NBINS partials (2MB)
    float* out = (float*)d_out;

    hist_kernel<<<NPART, 256, 0, stream>>>(act, gC, out, rows);
    reduce_kernel<<<32, 256, 0, stream>>>(gC, out, 1.0f / (float)rows);
}

// Round 8
// 16.457 us; speedup vs baseline: 2.5735x; 2.3954x over previous
//
#include <hip/hip_runtime.h>
#include <hip/hip_bf16.h>
#include <math.h>

#define NBINS   1024
#define NPART   1024    // hist grid: 1024 blocks x 128 rows (2 waves x 64 rows)
#define NCHUNK  32
#define LSTRIDE 72      // ushorts per bin-row: 144B, 16B-aligned slots

typedef __attribute__((ext_vector_type(8)))  short short8;   // 8 bf16 = 4 VGPR
typedef __attribute__((ext_vector_type(16))) float f32x16;   // MFMA 32x32 acc

// R5 shell (verified 19.2us): 1024x128 hist -> 4MB partials -> reduce -> finalize.
// Only phase 2 changed to MFMA (validated correct in R7).
// ws layout: gC[1024*1024] partials (4MB) | g2[32*1024] chunk partials (128KB).
// No atomics anywhere; d_out written only by finalize (plain store).

__global__ __launch_bounds__(128, 2) void hist_kernel(const float* __restrict__ act,
                                                      float* __restrict__ gC,
                                                      int rows)
{
    // Per-wave bf16 operand panels [bin][row-slot]: phase-2 lane reads 8
    // consecutive row-slots of its bin as one 16B ds_read_b128.
    __shared__ ushort Phi_u[2][32][LSTRIDE];   // 9KB
    __shared__ ushort Plo_u[2][32][LSTRIDE];   // 9KB
    __shared__ float  C_lds[NBINS];            // 4KB  (22.5KB total)

    const int tid  = threadIdx.x;
    const int wav  = tid >> 6;
    const int lane = tid & 63;

    const int row = blockIdx.x * 128 + tid;

    float v[10];
    float valid = 1.0f;
    if (row < rows) {
        const float2* a2 = (const float2*)(act + (size_t)row * 10);
        #pragma unroll
        for (int k = 0; k < 5; ++k) {
            float2 t = a2[k];
            v[2 * k] = t.x; v[2 * k + 1] = t.y;
        }
    } else {
        valid = 0.0f;
        #pragma unroll
        for (int k = 0; k < 10; ++k) v[k] = 0.0f;
    }

    // Product trees (f32). r=0 is the MSB of the 10-bit joint index.
    float hi[32], lo[32];
    {
        float t2[2], t4[4], t8[8], t16[16];
        t2[0] = valid * (1.0f - v[0]); t2[1] = valid * v[0];
        #pragma unroll
        for (int k = 0; k < 4; ++k)  t4[k]  = t2[k >> 1]  * ((k & 1) ? v[1] : 1.0f - v[1]);
        #pragma unroll
        for (int k = 0; k < 8; ++k)  t8[k]  = t4[k >> 1]  * ((k & 1) ? v[2] : 1.0f - v[2]);
        #pragma unroll
        for (int k = 0; k < 16; ++k) t16[k] = t8[k >> 1]  * ((k & 1) ? v[3] : 1.0f - v[3]);
        #pragma unroll
        for (int k = 0; k < 32; ++k) hi[k]  = t16[k >> 1] * ((k & 1) ? v[4] : 1.0f - v[4]);
    }
    {
        float t2[2], t4[4], t8[8], t16[16];
        t2[0] = 1.0f - v[5]; t2[1] = v[5];
        #pragma unroll
        for (int k = 0; k < 4; ++k)  t4[k]  = t2[k >> 1]  * ((k & 1) ? v[6] : 1.0f - v[6]);
        #pragma unroll
        for (int k = 0; k < 8; ++k)  t8[k]  = t4[k >> 1]  * ((k & 1) ? v[7] : 1.0f - v[7]);
        #pragma unroll
        for (int k = 0; k < 16; ++k) t16[k] = t8[k >> 1]  * ((k & 1) ? v[8] : 1.0f - v[8]);
        #pragma unroll
        for (int k = 0; k < 32; ++k) lo[k]  = t16[k >> 1] * ((k & 1) ? v[9] : 1.0f - v[9]);
    }

    // Stage as bf16. Per instruction: lanes hit banks (lane/2)%32 pairwise within
    // one dword -> conflict-free.
    #pragma unroll
    for (int m = 0; m < 32; ++m) {
        __hip_bfloat16 bh = __float2bfloat16(hi[m]);
        __hip_bfloat16 bl = __float2bfloat16(lo[m]);
        Phi_u[wav][m][lane] = *(const ushort*)&bh;
        Plo_u[wav][m][lane] = *(const ushort*)&bl;
    }

    __syncthreads();

    // Phase 2 (validated in R7): C(32x32) += Phi^T * Plo over this wave's 64 rows
    // via 4x mfma_f32_32x32x16_bf16. A: m=lane%32, k=(lane>>5)*8+i; B mirrored.
    // (m,n)->bin bijection is irrelevant (entropy is bin-symmetric); only
    // cross-wave/block consistency of the merge indexing matters.
    const int m  = lane & 31;
    const int kh = (lane >> 5) * 8;      // 0 or 8

    f32x16 acc = {};
    #pragma unroll
    for (int t = 0; t < 4; ++t) {
        const short8 a = *(const short8*)&Phi_u[wav][m][kh + 16 * t];  // 16B aligned
        const short8 b = *(const short8*)&Plo_u[wav][m][kh + 16 * t];
        acc = __builtin_amdgcn_mfma_f32_32x32x16_bf16(a, b, acc, 0, 0, 0);
    }

    // Merge 2 waves without atomics: wave1 stores, wave0 adds.
    // Banks = lane%32 -> 2 lanes/bank = free.
    if (wav == 1) {
        #pragma unroll
        for (int r = 0; r < 16; ++r)
            C_lds[r * 64 + lane] = acc[r];
    }
    __syncthreads();
    if (wav == 0) {
        #pragma unroll
        for (int r = 0; r < 16; ++r)
            C_lds[r * 64 + lane] += acc[r];
    }
    __syncthreads();

    // coalesced plain-store of the block's 4KB partial (no global atomics)
    float4* dst4 = (float4*)(gC + (size_t)blockIdx.x * NBINS);
    const float4* src4 = (const float4*)C_lds;
    dst4[tid]       = src4[tid];
    dst4[tid + 128] = src4[tid + 128];
}

// Sum 1024 block-partials -> 32 chunk-partials. 128 blocks x 256 threads. (R5)
__global__ __launch_bounds__(256) void reduce_kernel(const float* __restrict__ gC,
                                                     float* __restrict__ g2)
{
    const int chunk = blockIdx.x >> 2;                    // 0..31
    const int bin   = (blockIdx.x & 3) * 256 + threadIdx.x;
    const float* p  = gC + (size_t)chunk * 32 * NBINS + bin;
    float s = 0.0f;
    #pragma unroll
    for (int k = 0; k < 32; ++k) s += p[k * NBINS];       // coalesced across threads
    g2[chunk * NBINS + bin] = s;
}

__global__ __launch_bounds__(256) void finalize_kernel(const float* __restrict__ g2,
                                                       float* __restrict__ out,
                                                       float invB)
{
    __shared__ float red[4];
    const int tid = threadIdx.x;

    float4 acc = make_float4(0.f, 0.f, 0.f, 0.f);
    #pragma unroll
    for (int s = 0; s < NCHUNK; ++s) {
        const float4 t = *(const float4*)&g2[s * NBINS + tid * 4];
        acc.x += t.x; acc.y += t.y; acc.z += t.z; acc.w += t.w;
    }

    float s = 0.0f;
    const float b[4] = {acc.x, acc.y, acc.z, acc.w};
    #pragma unroll
    for (int k = 0; k < 4; ++k) {
        const float p  = b[k] * invB;
        const float ps = fmaxf(p, 1e-12f);
        s += p * log2f(ps);   // out = sum p*log2(clip(p)) = -joint_h
    }
    #pragma unroll
    for (int off = 32; off > 0; off >>= 1) s += __shfl_down(s, off);
    if ((tid & 63) == 0) red[tid >> 6] = s;
    __syncthreads();
    if (tid == 0) out[0] = red[0] + red[1] + red[2] + red[3];
}

extern "C" void kernel_launch(void* const* d_in, const int* in_sizes, int n_in,
                              void* d_out, int out_size, void* d_ws, size_t ws_size,
                              hipStream_t stream)
{
    const float* act = (const float*)d_in[0];
    const int rows = in_sizes[0] / 10;        // B = 131072
    float* gC = (float*)d_ws;                 // 1024 x 1024 block partials (4MB)
    float* g2 = gC + 1024 * NBINS;            // 32 x 1024 chunk partials (128KB)

    hist_kernel<<<NPART, 128, 0, stream>>>(act, gC, rows);
    reduce_kernel<<<128, 256, 0, stream>>>(gC, g2);
    finalize_kernel<<<1, 256, 0, stream>>>(g2, (float*)d_out, 1.0f / (float)rows);
}